// Round 3
// baseline (245.436 us; speedup 1.0000x reference)
//
#include <hip/hip_runtime.h>
#include <hip/hip_bf16.h>

// Problem constants
#define BB 8
#define TT 2048
#define EE 1024
#define HH 64

typedef __attribute__((ext_vector_type(8))) short short8;
typedef __attribute__((ext_vector_type(4))) float f32x4;

__device__ inline f32x4 mfma_16x16x32(short8 a, short8 b, f32x4 c) {
  return __builtin_amdgcn_mfma_f32_16x16x32_bf16(a, b, c, 0, 0, 0);
}

// async global->LDS, 16B per lane, LDS dest = wave-uniform base + lane*16
__device__ inline void gload_lds16(const __hip_bfloat16* g, __hip_bfloat16* l) {
  __builtin_amdgcn_global_load_lds((const __attribute__((address_space(1))) void*)g,
                                   (__attribute__((address_space(3))) void*)l,
                                   16, 0, 0);
}

__device__ inline short f2bf(float f) {
  __hip_bfloat16 h = __float2bfloat16(f);
  return *reinterpret_cast<short*>(&h);
}
__device__ inline float bf2f(short s) {
  __hip_bfloat16 h = *reinterpret_cast<__hip_bfloat16*>(&s);
  return __bfloat162float(h);
}

// wait lgkmcnt(0) only; leave vmcnt/expcnt unconstrained
#define WAIT_LGKM0() __builtin_amdgcn_s_waitcnt(0xC07F)

// ---------------------------------------------------------------------------
// Kernel 0: split-precision transposed weights (unchanged).
// ---------------------------------------------------------------------------
__global__ void prep_w(const float* __restrict__ Wq, const float* __restrict__ Wk,
                       const float* __restrict__ Wv,
                       __hip_bfloat16* __restrict__ Wthi,
                       __hip_bfloat16* __restrict__ Wtlo) {
  const int n = blockIdx.x;          // 0..191
  const int m = n >> 6;
  const int h = n & 63;
  const float* W = (m == 0) ? Wq : (m == 1) ? Wk : Wv;
  const int e0 = threadIdx.x * 4;    // 256 threads * 4 = 1024
#pragma unroll
  for (int j = 0; j < 4; ++j) {
    const float w = W[(e0 + j) * 64 + h];
    const __hip_bfloat16 hi = __float2bfloat16(w);
    Wthi[n * 1024 + e0 + j] = hi;
    Wtlo[n * 1024 + e0 + j] = __float2bfloat16(w - __bfloat162float(hi));
  }
}

// ---------------------------------------------------------------------------
// Kernel A v2 (unchanged this round): 512 blocks x 32 rows, Blo in registers.
// ---------------------------------------------------------------------------
__global__ __launch_bounds__(256) void qkv_gemm(
    const float* __restrict__ x,
    const __hip_bfloat16* __restrict__ Wthi, const __hip_bfloat16* __restrict__ Wtlo,
    __hip_bfloat16* __restrict__ qhi, __hip_bfloat16* __restrict__ qlo,
    __hip_bfloat16* __restrict__ khi, __hip_bfloat16* __restrict__ klo,
    __hip_bfloat16* __restrict__ vT) {
  __shared__ __hip_bfloat16 Ahi[2][32 * 72];
  __shared__ __hip_bfloat16 Alo[2][32 * 72];
  __shared__ __hip_bfloat16 Bhi[2][192 * 64];

  const int tid  = threadIdx.x;
  const int wave = tid >> 6;
  const int lane = tid & 63;
  const int row0 = blockIdx.x * 32;
  const int l15 = lane & 15, l4 = lane >> 4;

  const int lr = tid >> 3;           // 0..31 (row in strip)
  const int le = (tid & 7) * 8;      // 0..56 (col, floats)
  const float* xrow = x + (row0 + lr) * 1024 + le;

  f32x4 acc[2][3];
#pragma unroll
  for (int m = 0; m < 2; ++m)
#pragma unroll
    for (int j = 0; j < 3; ++j) acc[m][j] = f32x4{0.f, 0.f, 0.f, 0.f};

  // wave w stages only its own j-groups of Bhi (6 quads: 2 per j-group)
  auto issue_Bhi = [&](int c, int buf) {
    const int g = (lane & 7) ^ ((lane >> 3) & 7);
#pragma unroll
    for (int s = 0; s < 3; ++s) {
      const int j = wave + s * 4;
#pragma unroll
      for (int qh = 0; qh < 2; ++qh) {
        const int qq = j * 2 + qh;
        const int n  = qq * 8 + (lane >> 3);
        gload_lds16(Wthi + n * 1024 + c * 64 + g * 8, &Bhi[buf][qq * 512]);
      }
    }
  };
  // lo-correction B frags straight to registers (j=w and j=w+4, both < 8)
  auto load_Blo = [&](int c, short8* bl) {
#pragma unroll
    for (int jj = 0; jj < 2; ++jj) {
      const int j = wave + jj * 4;
      const __hip_bfloat16* p = Wtlo + (j * 16 + l15) * 1024 + c * 64;
      bl[jj * 2]     = *(const short8*)(p + l4 * 8);
      bl[jj * 2 + 1] = *(const short8*)(p + 32 + l4 * 8);
    }
  };
  auto write_A = [&](int buf, const f32x4* xr) {
    short8 h0, l0;
    const float* xf = (const float*)xr;
#pragma unroll
    for (int j = 0; j < 8; ++j) {
      const float v = xf[j];
      const short h = f2bf(v);
      h0[j] = h;
      l0[j] = f2bf(v - bf2f(h));
    }
    *(short8*)&Ahi[buf][lr * 72 + le] = h0;
    *(short8*)&Alo[buf][lr * 72 + le] = l0;
  };
  auto compute = [&](int buf, const short8* bl) {
#pragma unroll
    for (int m = 0; m < 2; ++m) {
      const int tr = m * 16 + l15;
      short8 ah0 = *(const short8*)&Ahi[buf][tr * 72 + l4 * 8];
      short8 ah1 = *(const short8*)&Ahi[buf][tr * 72 + 32 + l4 * 8];
      short8 al0 = *(const short8*)&Alo[buf][tr * 72 + l4 * 8];
      short8 al1 = *(const short8*)&Alo[buf][tr * 72 + 32 + l4 * 8];
#pragma unroll
      for (int jj = 0; jj < 3; ++jj) {
        const int j  = (jj < 2) ? (wave + jj * 4) : (wave + 8);
        const int n  = j * 16 + l15;
        const int o0 = ((l4)     ^ (n & 7)) * 8;
        const int o1 = ((4 + l4) ^ (n & 7)) * 8;
        short8 bh0 = *(const short8*)&Bhi[buf][n * 64 + o0];
        short8 bh1 = *(const short8*)&Bhi[buf][n * 64 + o1];
        acc[m][jj] = mfma_16x16x32(ah0, bh0, acc[m][jj]);
        acc[m][jj] = mfma_16x16x32(ah1, bh1, acc[m][jj]);
        if (jj < 2) {
          acc[m][jj] = mfma_16x16x32(ah0, bl[jj * 2],     acc[m][jj]);
          acc[m][jj] = mfma_16x16x32(ah1, bl[jj * 2 + 1], acc[m][jj]);
          acc[m][jj] = mfma_16x16x32(al0, bh0, acc[m][jj]);
          acc[m][jj] = mfma_16x16x32(al1, bh1, acc[m][jj]);
        }
      }
    }
  };

  f32x4 xr[2], xn[2];
  {
    const f32x4* p = (const f32x4*)xrow;
    xr[0] = p[0]; xr[1] = p[1];
  }
  short8 blc[4], bln[4];
  issue_Bhi(0, 0);
  load_Blo(0, blc);
  __builtin_amdgcn_s_waitcnt(0);
  write_A(0, xr);
  __syncthreads();

  for (int c = 0; c < 16; ++c) {
    const int p = c & 1;
    if (c < 15) {
      const f32x4* pp = (const f32x4*)(xrow + (c + 1) * 64);
      xn[0] = pp[0]; xn[1] = pp[1];
      issue_Bhi(c + 1, p ^ 1);
      load_Blo(c + 1, bln);
    }
    compute(p, blc);
    if (c < 15) {
      __builtin_amdgcn_s_waitcnt(0);
      write_A(p ^ 1, xn);
#pragma unroll
      for (int q = 0; q < 4; ++q) blc[q] = bln[q];
    }
    __syncthreads();
  }

  // Epilogue: wave w wrote cols w*16+l15 of q (jj=0), k (jj=1), v (jj=2)
  const int hcol = wave * 16 + l15;
#pragma unroll
  for (int jj = 0; jj < 3; ++jj) {
#pragma unroll
    for (int m = 0; m < 2; ++m) {
#pragma unroll
      for (int r = 0; r < 4; ++r) {
        const int trow = row0 + m * 16 + l4 * 4 + r;
        const float val = acc[m][jj][r];
        if (jj == 0) {
          const __hip_bfloat16 hi = __float2bfloat16(val);
          qhi[trow * 64 + hcol] = hi;
          qlo[trow * 64 + hcol] = __float2bfloat16(val - __bfloat162float(hi));
        } else if (jj == 1) {
          const __hip_bfloat16 hi = __float2bfloat16(val);
          khi[trow * 64 + hcol] = hi;
          klo[trow * 64 + hcol] = __float2bfloat16(val - __bfloat162float(hi));
        } else {
          const int bb = trow >> 11, tl = trow & 2047;
          vT[(bb * 64 + hcol) * 2048 + tl] = __float2bfloat16(val);
        }
      }
    }
  }
}

// ---------------------------------------------------------------------------
// Kernel B v8: PAIRED 16-row strips for uniform work (v7 regression fixes).
// Block = (batch, pp): processes strip 127-pp then strip pp sequentially;
// pair work = (pp/4+1)+((127-pp)/4+1) ~ 33 tiles for EVERY block -> no tail.
// Grid 512 (2 blocks/CU, 8 waves/CU). K loads BATCHED up front per tile
// (v7's per-j loads exposed 4x L2 latency -> 61us); V loads hoisted before
// softmax so softmax hides their latency. launch_bounds(256,4): peak live
// regs ~116 <= 128 cap.
// ---------------------------------------------------------------------------
__global__ __launch_bounds__(256, 4) void attn(
    const __hip_bfloat16* __restrict__ qhi, const __hip_bfloat16* __restrict__ qlo,
    const __hip_bfloat16* __restrict__ khi, const __hip_bfloat16* __restrict__ klo,
    const __hip_bfloat16* __restrict__ vT, float* __restrict__ out) {
  __shared__ __hip_bfloat16 Psm[4][16 * 72];  // per-wave P transpose
  __shared__ float Osm[4][16][65];            // per-wave partial O (fp32)
  __shared__ float Msm[4][16];
  __shared__ float Lsm[4][16];

  const int tid  = threadIdx.x;
  const int wave = tid >> 6;
  const int lane = tid & 63;
  const int l15 = lane & 15, l4 = lane >> 4;

  const int b  = blockIdx.x & 7;             // XCD-local batch
  const int pp = blockIdx.x >> 3;            // 0..63 pair index

  const __hip_bfloat16* kbase_h = khi + (size_t)b * 2048 * 64;
  const __hip_bfloat16* kbase_l = klo + (size_t)b * 2048 * 64;
  const __hip_bfloat16* vbase   = vT + (size_t)b * 64 * 2048;

  for (int half = 0; half < 2; ++half) {
    const int ss = half ? pp : (127 - pp);   // big strip first
    const int t0 = ss * 16;
    const int ntiles = (ss >> 2) + 1;        // causal 64-key tiles

    // ---- Q A-frags, hi+lo (16 VGPRs) ----
    const __hip_bfloat16* qph = qhi + (b * 2048 + t0 + l15) * 64;
    const __hip_bfloat16* qpl = qlo + (b * 2048 + t0 + l15) * 64;
    const short8 qh0 = *(const short8*)(qph + l4 * 8);
    const short8 qh1 = *(const short8*)(qph + 32 + l4 * 8);
    const short8 ql0 = *(const short8*)(qpl + l4 * 8);
    const short8 ql1 = *(const short8*)(qpl + 32 + l4 * 8);

    f32x4 acc[4];
#pragma unroll
    for (int j = 0; j < 4; ++j) acc[j] = f32x4{0.f, 0.f, 0.f, 0.f};
    float m_[4], l_[4];
#pragma unroll
    for (int r = 0; r < 4; ++r) { m_[r] = -1e30f; l_[r] = 0.f; }

    // ---- K-loop: wave takes tiles wave, wave+4, ... ----
    for (int kt = wave; kt < ntiles; kt += 4) {
      const int k0 = kt << 6;
      const bool diag = (kt == ntiles - 1);

      // Batched K frags for all live j-groups (issued back-to-back: one
      // exposed L2 latency per tile, not four).
      short8 kh0[4], kh1[4], kl0[4], kl1[4];
#pragma unroll
      for (int j = 0; j < 4; ++j) {
        if (!(diag && (k0 + j * 16) > (t0 + 15))) {
          const __hip_bfloat16* kph = kbase_h + (k0 + j * 16 + l15) * 64;
          const __hip_bfloat16* kpl = kbase_l + (k0 + j * 16 + l15) * 64;
          kh0[j] = *(const short8*)(kph + l4 * 8);
          kh1[j] = *(const short8*)(kph + 32 + l4 * 8);
          kl0[j] = *(const short8*)(kpl + l4 * 8);
          kl1[j] = *(const short8*)(kpl + 32 + l4 * 8);
        }
      }

      f32x4 s_[4];
#pragma unroll
      for (int j = 0; j < 4; ++j) {
        if (diag && (k0 + j * 16) > (t0 + 15)) {
          s_[j] = f32x4{-1e30f, -1e30f, -1e30f, -1e30f};
        } else {
          f32x4 z = f32x4{0.f, 0.f, 0.f, 0.f};
          z = mfma_16x16x32(qh0, kh0[j], z);
          z = mfma_16x16x32(qh1, kh1[j], z);
          z = mfma_16x16x32(qh0, kl0[j], z);
          z = mfma_16x16x32(qh1, kl1[j], z);
          z = mfma_16x16x32(ql0, kh0[j], z);
          z = mfma_16x16x32(ql1, kh1[j], z);
          s_[j] = z;
        }
      }

      // ---- V frags issued NOW: softmax below hides their latency ----
      short8 vf0[4], vf1[4];
#pragma unroll
      for (int j = 0; j < 4; ++j) {
        const __hip_bfloat16* vp = vbase + (j * 16 + l15) * 2048 + k0;
        vf0[j] = *(const short8*)(vp + l4 * 8);
        vf1[j] = *(const short8*)(vp + 32 + l4 * 8);
      }

      if (diag) {   // partial mask where key > row
#pragma unroll
        for (int j = 0; j < 4; ++j) {
          const int key = k0 + j * 16 + l15;
#pragma unroll
          for (int r = 0; r < 4; ++r) {
            const int row = t0 + l4 * 4 + r;
            if (key > row) s_[j][r] = -1e30f;
          }
        }
      }

      // online softmax (4 rows/lane; reduce across 16-lane col groups)
      float mx[4], rs[4], al[4];
#pragma unroll
      for (int r = 0; r < 4; ++r)
        mx[r] = fmaxf(fmaxf(s_[0][r], s_[1][r]), fmaxf(s_[2][r], s_[3][r]));
      for (int off = 1; off < 16; off <<= 1) {
#pragma unroll
        for (int r = 0; r < 4; ++r) mx[r] = fmaxf(mx[r], __shfl_xor(mx[r], off));
      }
#pragma unroll
      for (int r = 0; r < 4; ++r) {
        const float mn = fmaxf(m_[r], mx[r]);
        al[r] = __expf(m_[r] - mn);
        m_[r] = mn;
        rs[r] = 0.f;
      }
#pragma unroll
      for (int j = 0; j < 4; ++j) {
#pragma unroll
        for (int r = 0; r < 4; ++r) {
          const float pv = __expf(s_[j][r] - m_[r]);
          s_[j][r] = pv;
          rs[r] += pv;
        }
      }
      for (int off = 1; off < 16; off <<= 1) {
#pragma unroll
        for (int r = 0; r < 4; ++r) rs[r] += __shfl_xor(rs[r], off);
      }
#pragma unroll
      for (int r = 0; r < 4; ++r) l_[r] = l_[r] * al[r] + rs[r];
#pragma unroll
      for (int j = 0; j < 4; ++j)
#pragma unroll
        for (int r = 0; r < 4; ++r) acc[j][r] *= al[r];

      // P (C-layout) -> per-wave LDS buffer
#pragma unroll
      for (int j = 0; j < 4; ++j)
#pragma unroll
        for (int r = 0; r < 4; ++r)
          Psm[wave][(l4 * 4 + r) * 72 + j * 16 + l15] = __float2bfloat16(s_[j][r]);

      WAIT_LGKM0();   // P LDS writes visible to same wave; vmcnt untouched

      // ---- O += P V ----
      const short8 pf0 = *(const short8*)&Psm[wave][l15 * 72 + l4 * 8];
      const short8 pf1 = *(const short8*)&Psm[wave][l15 * 72 + 32 + l4 * 8];
#pragma unroll
      for (int j = 0; j < 4; ++j) {
        acc[j] = mfma_16x16x32(pf0, vf0[j], acc[j]);
        acc[j] = mfma_16x16x32(pf1, vf1[j], acc[j]);
      }
    }

    // ---- per-wave partials into LDS (fp32) ----
#pragma unroll
    for (int j = 0; j < 4; ++j)
#pragma unroll
      for (int r = 0; r < 4; ++r)
        Osm[wave][l4 * 4 + r][j * 16 + l15] = acc[j][r];
    if (l15 == 0) {
#pragma unroll
      for (int r = 0; r < 4; ++r) {
        Msm[wave][l4 * 4 + r] = m_[r];
        Lsm[wave][l4 * 4 + r] = l_[r];
      }
    }
    __syncthreads();

    // ---- cross-wave merge: wave handles rows [wave*4, +4), lane = h ----
#pragma unroll
    for (int rr = 0; rr < 4; ++rr) {
      const int row = wave * 4 + rr;
      float M = fmaxf(fmaxf(Msm[0][row], Msm[1][row]),
                      fmaxf(Msm[2][row], Msm[3][row]));
      float L = 0.f, O = 0.f;
#pragma unroll
      for (int w2 = 0; w2 < 4; ++w2) {
        const float a = __expf(Msm[w2][row] - M);
        L += a * Lsm[w2][row];
        O += a * Osm[w2][row][lane];
      }
      out[(b * 2048 + t0 + row) * 64 + lane] = O / L;
    }
    __syncthreads();   // protect Osm/Msm/Lsm reuse by next strip
  }
}

// ---------------------------------------------------------------------------
extern "C" void kernel_launch(void* const* d_in, const int* in_sizes, int n_in,
                              void* d_out, int out_size, void* d_ws, size_t ws_size,
                              hipStream_t stream) {
  const float* x  = (const float*)d_in[0];
  const float* Wq = (const float*)d_in[1];
  const float* Wk = (const float*)d_in[2];
  const float* Wv = (const float*)d_in[3];
  float* out = (float*)d_out;

  char* ws = (char*)d_ws;
  __hip_bfloat16* Wthi = (__hip_bfloat16*)ws;                   // 384 KB
  __hip_bfloat16* Wtlo = (__hip_bfloat16*)(ws + 393216);        // 384 KB
  __hip_bfloat16* qhi  = (__hip_bfloat16*)(ws + 786432);        // 2 MB each
  __hip_bfloat16* qlo  = (__hip_bfloat16*)(ws + 786432 + 1 * 2097152);
  __hip_bfloat16* khi  = (__hip_bfloat16*)(ws + 786432 + 2 * 2097152);
  __hip_bfloat16* klo  = (__hip_bfloat16*)(ws + 786432 + 3 * 2097152);
  __hip_bfloat16* vT   = (__hip_bfloat16*)(ws + 786432 + 4 * 2097152);

  prep_w<<<192, 256, 0, stream>>>(Wq, Wk, Wv, Wthi, Wtlo);
  qkv_gemm<<<512, 256, 0, stream>>>(x, Wthi, Wtlo, qhi, qlo, khi, klo, vT);
  attn<<<512, 256, 0, stream>>>(qhi, qlo, khi, klo, vT, out);  // 8 b x 64 pairs
}

// Round 6
// 184.907 us; speedup vs baseline: 1.3273x; 1.3273x over previous
//
#include <hip/hip_runtime.h>
#include <hip/hip_bf16.h>

// Problem constants
#define BB 8
#define TT 2048
#define EE 1024
#define HH 64

typedef __attribute__((ext_vector_type(8))) short short8;
typedef __attribute__((ext_vector_type(4))) float f32x4;

__device__ inline f32x4 mfma_16x16x32(short8 a, short8 b, f32x4 c) {
  return __builtin_amdgcn_mfma_f32_16x16x32_bf16(a, b, c, 0, 0, 0);
}

// async global->LDS, 16B per lane, LDS dest = wave-uniform base + lane*16
__device__ inline void gload_lds16(const __hip_bfloat16* g, __hip_bfloat16* l) {
  __builtin_amdgcn_global_load_lds((const __attribute__((address_space(1))) void*)g,
                                   (__attribute__((address_space(3))) void*)l,
                                   16, 0, 0);
}

__device__ inline short f2bf(float f) {
  __hip_bfloat16 h = __float2bfloat16(f);
  return *reinterpret_cast<short*>(&h);
}
__device__ inline float bf2f(short s) {
  __hip_bfloat16 h = *reinterpret_cast<__hip_bfloat16*>(&s);
  return __bfloat162float(h);
}

// wait lgkmcnt(0) only; leave vmcnt/expcnt unconstrained
#define WAIT_LGKM0() __builtin_amdgcn_s_waitcnt(0xC07F)

// ---------------------------------------------------------------------------
// Kernel 0: split-precision transposed weights. Block 0 also zeroes maxk2
// (stream-ordered before knorm).
// ---------------------------------------------------------------------------
__global__ void prep_w(const float* __restrict__ Wq, const float* __restrict__ Wk,
                       const float* __restrict__ Wv,
                       __hip_bfloat16* __restrict__ Wthi,
                       __hip_bfloat16* __restrict__ Wtlo,
                       float* __restrict__ maxk2) {
  const int n = blockIdx.x;          // 0..191
  if (n == 0 && threadIdx.x < 8) maxk2[threadIdx.x] = 0.f;
  const int m = n >> 6;
  const int h = n & 63;
  const float* W = (m == 0) ? Wq : (m == 1) ? Wk : Wv;
  const int e0 = threadIdx.x * 4;    // 256 threads * 4 = 1024
#pragma unroll
  for (int j = 0; j < 4; ++j) {
    const float w = W[(e0 + j) * 64 + h];
    const __hip_bfloat16 hi = __float2bfloat16(w);
    Wthi[n * 1024 + e0 + j] = hi;
    Wtlo[n * 1024 + e0 + j] = __float2bfloat16(w - __bfloat162float(hi));
  }
}

// ---------------------------------------------------------------------------
// Kernel A v2 (unchanged): 512 blocks x 32 rows, Blo in registers.
// ---------------------------------------------------------------------------
__global__ __launch_bounds__(256) void qkv_gemm(
    const float* __restrict__ x,
    const __hip_bfloat16* __restrict__ Wthi, const __hip_bfloat16* __restrict__ Wtlo,
    __hip_bfloat16* __restrict__ qhi, __hip_bfloat16* __restrict__ qlo,
    __hip_bfloat16* __restrict__ khi, __hip_bfloat16* __restrict__ klo,
    __hip_bfloat16* __restrict__ vT) {
  __shared__ __hip_bfloat16 Ahi[2][32 * 72];
  __shared__ __hip_bfloat16 Alo[2][32 * 72];
  __shared__ __hip_bfloat16 Bhi[2][192 * 64];

  const int tid  = threadIdx.x;
  const int wave = tid >> 6;
  const int lane = tid & 63;
  const int row0 = blockIdx.x * 32;
  const int l15 = lane & 15, l4 = lane >> 4;

  const int lr = tid >> 3;           // 0..31 (row in strip)
  const int le = (tid & 7) * 8;      // 0..56 (col, floats)
  const float* xrow = x + (row0 + lr) * 1024 + le;

  f32x4 acc[2][3];
#pragma unroll
  for (int m = 0; m < 2; ++m)
#pragma unroll
    for (int j = 0; j < 3; ++j) acc[m][j] = f32x4{0.f, 0.f, 0.f, 0.f};

  // wave w stages only its own j-groups of Bhi (6 quads: 2 per j-group)
  auto issue_Bhi = [&](int c, int buf) {
    const int g = (lane & 7) ^ ((lane >> 3) & 7);
#pragma unroll
    for (int s = 0; s < 3; ++s) {
      const int j = wave + s * 4;
#pragma unroll
      for (int qh = 0; qh < 2; ++qh) {
        const int qq = j * 2 + qh;
        const int n  = qq * 8 + (lane >> 3);
        gload_lds16(Wthi + n * 1024 + c * 64 + g * 8, &Bhi[buf][qq * 512]);
      }
    }
  };
  // lo-correction B frags straight to registers (j=w and j=w+4, both < 8)
  auto load_Blo = [&](int c, short8* bl) {
#pragma unroll
    for (int jj = 0; jj < 2; ++jj) {
      const int j = wave + jj * 4;
      const __hip_bfloat16* p = Wtlo + (j * 16 + l15) * 1024 + c * 64;
      bl[jj * 2]     = *(const short8*)(p + l4 * 8);
      bl[jj * 2 + 1] = *(const short8*)(p + 32 + l4 * 8);
    }
  };
  auto write_A = [&](int buf, const f32x4* xr) {
    short8 h0, l0;
    const float* xf = (const float*)xr;
#pragma unroll
    for (int j = 0; j < 8; ++j) {
      const float v = xf[j];
      const short h = f2bf(v);
      h0[j] = h;
      l0[j] = f2bf(v - bf2f(h));
    }
    *(short8*)&Ahi[buf][lr * 72 + le] = h0;
    *(short8*)&Alo[buf][lr * 72 + le] = l0;
  };
  auto compute = [&](int buf, const short8* bl) {
#pragma unroll
    for (int m = 0; m < 2; ++m) {
      const int tr = m * 16 + l15;
      short8 ah0 = *(const short8*)&Ahi[buf][tr * 72 + l4 * 8];
      short8 ah1 = *(const short8*)&Ahi[buf][tr * 72 + 32 + l4 * 8];
      short8 al0 = *(const short8*)&Alo[buf][tr * 72 + l4 * 8];
      short8 al1 = *(const short8*)&Alo[buf][tr * 72 + 32 + l4 * 8];
#pragma unroll
      for (int jj = 0; jj < 3; ++jj) {
        const int j  = (jj < 2) ? (wave + jj * 4) : (wave + 8);
        const int n  = j * 16 + l15;
        const int o0 = ((l4)     ^ (n & 7)) * 8;
        const int o1 = ((4 + l4) ^ (n & 7)) * 8;
        short8 bh0 = *(const short8*)&Bhi[buf][n * 64 + o0];
        short8 bh1 = *(const short8*)&Bhi[buf][n * 64 + o1];
        acc[m][jj] = mfma_16x16x32(ah0, bh0, acc[m][jj]);
        acc[m][jj] = mfma_16x16x32(ah1, bh1, acc[m][jj]);
        if (jj < 2) {
          acc[m][jj] = mfma_16x16x32(ah0, bl[jj * 2],     acc[m][jj]);
          acc[m][jj] = mfma_16x16x32(ah1, bl[jj * 2 + 1], acc[m][jj]);
          acc[m][jj] = mfma_16x16x32(al0, bh0, acc[m][jj]);
          acc[m][jj] = mfma_16x16x32(al1, bh1, acc[m][jj]);
        }
      }
    }
  };

  f32x4 xr[2], xn[2];
  {
    const f32x4* p = (const f32x4*)xrow;
    xr[0] = p[0]; xr[1] = p[1];
  }
  short8 blc[4], bln[4];
  issue_Bhi(0, 0);
  load_Blo(0, blc);
  __builtin_amdgcn_s_waitcnt(0);
  write_A(0, xr);
  __syncthreads();

  for (int c = 0; c < 16; ++c) {
    const int p = c & 1;
    if (c < 15) {
      const f32x4* pp = (const f32x4*)(xrow + (c + 1) * 64);
      xn[0] = pp[0]; xn[1] = pp[1];
      issue_Bhi(c + 1, p ^ 1);
      load_Blo(c + 1, bln);
    }
    compute(p, blc);
    if (c < 15) {
      __builtin_amdgcn_s_waitcnt(0);
      write_A(p ^ 1, xn);
#pragma unroll
      for (int q = 0; q < 4; ++q) blc[q] = bln[q];
    }
    __syncthreads();
  }

  // Epilogue: wave w wrote cols w*16+l15 of q (jj=0), k (jj=1), v (jj=2)
  const int hcol = wave * 16 + l15;
#pragma unroll
  for (int jj = 0; jj < 3; ++jj) {
#pragma unroll
    for (int m = 0; m < 2; ++m) {
#pragma unroll
      for (int r = 0; r < 4; ++r) {
        const int trow = row0 + m * 16 + l4 * 4 + r;
        const float val = acc[m][jj][r];
        if (jj == 0) {
          const __hip_bfloat16 hi = __float2bfloat16(val);
          qhi[trow * 64 + hcol] = hi;
          qlo[trow * 64 + hcol] = __float2bfloat16(val - __bfloat162float(hi));
        } else if (jj == 1) {
          const __hip_bfloat16 hi = __float2bfloat16(val);
          khi[trow * 64 + hcol] = hi;
          klo[trow * 64 + hcol] = __float2bfloat16(val - __bfloat162float(hi));
        } else {
          const int bb = trow >> 11, tl = trow & 2047;
          vT[(bb * 64 + hcol) * 2048 + tl] = __float2bfloat16(val);
        }
      }
    }
  }
}

// ---------------------------------------------------------------------------
// Kernel K: per-batch max |k_row|^2 (fp32) via int-bits atomicMax (valid for
// non-negative floats). 64 blocks x 256 threads; thread = one row.
// ---------------------------------------------------------------------------
__global__ __launch_bounds__(256) void knorm(
    const __hip_bfloat16* __restrict__ khi, const __hip_bfloat16* __restrict__ klo,
    float* __restrict__ maxk2) {
  const int row = blockIdx.x * 256 + threadIdx.x;   // 0..16383
  const int b = row >> 11;
  const __hip_bfloat16* ph = khi + row * 64;
  const __hip_bfloat16* pl = klo + row * 64;
  float s = 0.f;
#pragma unroll
  for (int i = 0; i < 8; ++i) {
    const short8 h = *(const short8*)(ph + i * 8);
    const short8 l = *(const short8*)(pl + i * 8);
#pragma unroll
    for (int j = 0; j < 8; ++j) {
      const float v = bf2f(h[j]) + bf2f(l[j]);
      s += v * v;
    }
  }
  for (int off = 1; off < 64; off <<= 1) s = fmaxf(s, __shfl_xor(s, off));
  if ((threadIdx.x & 63) == 0)
    atomicMax((int*)&maxk2[b], __float_as_int(s));
}

// ---------------------------------------------------------------------------
// Kernel B v10: bound-subtracted no-max flash attention.
// v9 NaN'd: weights have positive mean -> rank-1 score component, scores up
// to ~300 >> 88 -> expf inf. Fix: p = exp(s - c_r) with the per-row
// Cauchy-Schwarz bound c_r = |q_r| * max_j|k_j| + 2. c_r is uniform per row
// (same for all tiles/waves), so plain-sum merge stays EXACT; normalization
// cancels c_r. Guarantees exp arg <= 0 (no overflow); overshoot <= ~40 ->
// p >= e^-40, well inside fp32/bf16 range (no underflow of L).
// Hot loop unchanged from v9: no shuffles, no rescale, MFMA row-sum.
// 16-row strips, grid 1024, lb(256,2) (NOT (256,4): pins VGPR=64 -> spills).
// ---------------------------------------------------------------------------
__global__ __launch_bounds__(256, 2) void attn(
    const __hip_bfloat16* __restrict__ qhi, const __hip_bfloat16* __restrict__ qlo,
    const __hip_bfloat16* __restrict__ khi, const __hip_bfloat16* __restrict__ klo,
    const __hip_bfloat16* __restrict__ vT, const float* __restrict__ maxk2,
    float* __restrict__ out) {
  __shared__ __hip_bfloat16 Psm[4][16 * 72];  // per-wave P transpose
  __shared__ float Osm[4][16][65];            // per-wave partial O (fp32)
  __shared__ float Lsm[4][16];                // per-wave partial L (plain sum)

  const int tid  = threadIdx.x;
  const int wave = tid >> 6;
  const int lane = tid & 63;
  const int l15 = lane & 15, l4 = lane >> 4;

  const int b  = blockIdx.x & 7;             // XCD-local batch
  const int ss = 127 - (blockIdx.x >> 3);    // 16-row strip, big-work first
  const int t0 = ss * 16;
  const int ntiles = (ss >> 2) + 1;          // causal 64-key tiles

  // ---- Q A-frags, hi+lo (16 VGPRs) ----
  const __hip_bfloat16* qph = qhi + (b * 2048 + t0 + l15) * 64;
  const __hip_bfloat16* qpl = qlo + (b * 2048 + t0 + l15) * 64;
  const short8 qh0 = *(const short8*)(qph + l4 * 8);
  const short8 qh1 = *(const short8*)(qph + 32 + l4 * 8);
  const short8 ql0 = *(const short8*)(qpl + l4 * 8);
  const short8 ql1 = *(const short8*)(qpl + 32 + l4 * 8);

  // ---- per-row score bound c_r = |q_r| * kmax + 2 (Cauchy-Schwarz) ----
  // Lane holds 16 of row (t0+l15)'s 64 cols; 4-lane group (l4) covers the row.
  float qn = 0.f;
#pragma unroll
  for (int i = 0; i < 8; ++i) {
    const float v0 = bf2f(qh0[i]) + bf2f(ql0[i]);
    const float v1 = bf2f(qh1[i]) + bf2f(ql1[i]);
    qn += v0 * v0 + v1 * v1;
  }
  qn += __shfl_xor(qn, 16);
  qn += __shfl_xor(qn, 32);                  // |q_{t0+l15}|^2 on all 4 lanes
  const float kmax = sqrtf(maxk2[b]);
  const float crow = sqrtf(qn) * kmax + 2.0f;  // bound for row t0+l15
  // Redistribute to C-layout rows (l4*4+r): source lane l4*4+r (<16)
  float c_[4];
#pragma unroll
  for (int r = 0; r < 4; ++r) c_[r] = __shfl(crow, l4 * 4 + r);

  short8 ones;                                // bf16 1.0 x8 (B-frag for L)
#pragma unroll
  for (int i = 0; i < 8; ++i) ones[i] = (short)0x3F80;

  f32x4 acc[4];
#pragma unroll
  for (int j = 0; j < 4; ++j) acc[j] = f32x4{0.f, 0.f, 0.f, 0.f};
  f32x4 accL = f32x4{0.f, 0.f, 0.f, 0.f};

  const __hip_bfloat16* kbase_h = khi + (size_t)b * 2048 * 64;
  const __hip_bfloat16* kbase_l = klo + (size_t)b * 2048 * 64;
  const __hip_bfloat16* vbase   = vT + (size_t)b * 64 * 2048;

  // ---- K-loop: wave takes tiles wave, wave+4, ... ----
  for (int kt = wave; kt < ntiles; kt += 4) {
    const int k0 = kt << 6;
    const bool diag = (kt == ntiles - 1);

    f32x4 s_[4];
    // Two stages of j-pairs: caps K regs at 32 live.
#pragma unroll
    for (int st = 0; st < 2; ++st) {
      short8 kh0[2], kh1[2], kl0[2], kl1[2];
#pragma unroll
      for (int jj = 0; jj < 2; ++jj) {
        const int j = st * 2 + jj;
        if (!(diag && (k0 + j * 16) > (t0 + 15))) {
          const __hip_bfloat16* kph = kbase_h + (k0 + j * 16 + l15) * 64;
          const __hip_bfloat16* kpl = kbase_l + (k0 + j * 16 + l15) * 64;
          kh0[jj] = *(const short8*)(kph + l4 * 8);
          kh1[jj] = *(const short8*)(kph + 32 + l4 * 8);
          kl0[jj] = *(const short8*)(kpl + l4 * 8);
          kl1[jj] = *(const short8*)(kpl + 32 + l4 * 8);
        }
      }
#pragma unroll
      for (int jj = 0; jj < 2; ++jj) {
        const int j = st * 2 + jj;
        if (diag && (k0 + j * 16) > (t0 + 15)) {
          s_[j] = f32x4{-1e30f, -1e30f, -1e30f, -1e30f};  // exp -> 0
        } else {
          f32x4 z = f32x4{0.f, 0.f, 0.f, 0.f};
          z = mfma_16x16x32(qh0, kh0[jj], z);
          z = mfma_16x16x32(qh1, kh1[jj], z);
          z = mfma_16x16x32(qh0, kl0[jj], z);
          z = mfma_16x16x32(qh1, kl1[jj], z);
          z = mfma_16x16x32(ql0, kh0[jj], z);
          z = mfma_16x16x32(ql1, kh1[jj], z);
          s_[j] = z;
        }
      }
    }

    if (diag) {   // partial mask where key > row (exp -> 0)
#pragma unroll
      for (int j = 0; j < 4; ++j) {
        const int key = k0 + j * 16 + l15;
#pragma unroll
        for (int r = 0; r < 4; ++r) {
          const int row = t0 + l4 * 4 + r;
          if (key > row) s_[j][r] = -1e30f;
        }
      }
    }

    // p = exp(s - c_r): bound-subtracted, no shuffles, no rescale
#pragma unroll
    for (int j = 0; j < 4; ++j)
#pragma unroll
      for (int r = 0; r < 4; ++r) s_[j][r] = __expf(s_[j][r] - c_[r]);

    // P (C-layout) -> per-wave LDS transpose buffer
#pragma unroll
    for (int j = 0; j < 4; ++j)
#pragma unroll
      for (int r = 0; r < 4; ++r)
        Psm[wave][(l4 * 4 + r) * 72 + j * 16 + l15] = __float2bfloat16(s_[j][r]);

    // ---- V frags: latency overlaps the lgkm wait + P reads ----
    short8 vf0[4], vf1[4];
#pragma unroll
    for (int j = 0; j < 4; ++j) {
      const __hip_bfloat16* vp = vbase + (j * 16 + l15) * 2048 + k0;
      vf0[j] = *(const short8*)(vp + l4 * 8);
      vf1[j] = *(const short8*)(vp + 32 + l4 * 8);
    }

    WAIT_LGKM0();   // P LDS writes visible to same wave; vmcnt untouched

    // ---- O += P V ; L += P . 1 (row-sum via MFMA) ----
    const short8 pf0 = *(const short8*)&Psm[wave][l15 * 72 + l4 * 8];
    const short8 pf1 = *(const short8*)&Psm[wave][l15 * 72 + 32 + l4 * 8];
#pragma unroll
    for (int j = 0; j < 4; ++j) {
      acc[j] = mfma_16x16x32(pf0, vf0[j], acc[j]);
      acc[j] = mfma_16x16x32(pf1, vf1[j], acc[j]);
    }
    accL = mfma_16x16x32(pf0, ones, accL);
    accL = mfma_16x16x32(pf1, ones, accL);
  }

  // ---- per-wave partials into LDS (fp32, plain sums) ----
#pragma unroll
  for (int j = 0; j < 4; ++j)
#pragma unroll
    for (int r = 0; r < 4; ++r)
      Osm[wave][l4 * 4 + r][j * 16 + l15] = acc[j][r];
  if (l15 == 0) {
#pragma unroll
    for (int r = 0; r < 4; ++r) Lsm[wave][l4 * 4 + r] = accL[r];
  }
  __syncthreads();

  // ---- cross-wave merge: PLAIN SUM (c_r uniform per row -> exact) ----
#pragma unroll
  for (int rr = 0; rr < 4; ++rr) {
    const int row = wave * 4 + rr;
    const float L = Lsm[0][row] + Lsm[1][row] + Lsm[2][row] + Lsm[3][row];
    float O = Osm[0][row][lane] + Osm[1][row][lane] +
              Osm[2][row][lane] + Osm[3][row][lane];
    out[(b * 2048 + t0 + row) * 64 + lane] = O / L;
  }
}

// ---------------------------------------------------------------------------
extern "C" void kernel_launch(void* const* d_in, const int* in_sizes, int n_in,
                              void* d_out, int out_size, void* d_ws, size_t ws_size,
                              hipStream_t stream) {
  const float* x  = (const float*)d_in[0];
  const float* Wq = (const float*)d_in[1];
  const float* Wk = (const float*)d_in[2];
  const float* Wv = (const float*)d_in[3];
  float* out = (float*)d_out;

  char* ws = (char*)d_ws;
  __hip_bfloat16* Wthi = (__hip_bfloat16*)ws;                   // 384 KB
  __hip_bfloat16* Wtlo = (__hip_bfloat16*)(ws + 393216);        // 384 KB
  __hip_bfloat16* qhi  = (__hip_bfloat16*)(ws + 786432);        // 2 MB each
  __hip_bfloat16* qlo  = (__hip_bfloat16*)(ws + 786432 + 1 * 2097152);
  __hip_bfloat16* khi  = (__hip_bfloat16*)(ws + 786432 + 2 * 2097152);
  __hip_bfloat16* klo  = (__hip_bfloat16*)(ws + 786432 + 3 * 2097152);
  __hip_bfloat16* vT   = (__hip_bfloat16*)(ws + 786432 + 4 * 2097152);
  float* maxk2         = (float*)(ws + 786432 + 5 * 2097152);   // 32 B

  prep_w<<<192, 256, 0, stream>>>(Wq, Wk, Wv, Wthi, Wtlo, maxk2);
  qkv_gemm<<<512, 256, 0, stream>>>(x, Wthi, Wtlo, qhi, qlo, khi, klo, vT);
  knorm<<<64, 256, 0, stream>>>(khi, klo, maxk2);
  attn<<<1024, 256, 0, stream>>>(qhi, qlo, khi, klo, vT, maxk2, out);
}

// Round 7
// 162.601 us; speedup vs baseline: 1.5094x; 1.1372x over previous
//
#include <hip/hip_runtime.h>
#include <hip/hip_bf16.h>

// Problem constants
#define BB 8
#define TT 2048
#define EE 1024
#define HH 64

typedef __attribute__((ext_vector_type(8))) short short8;
typedef __attribute__((ext_vector_type(4))) float f32x4;

__device__ inline f32x4 mfma_16x16x32(short8 a, short8 b, f32x4 c) {
  return __builtin_amdgcn_mfma_f32_16x16x32_bf16(a, b, c, 0, 0, 0);
}

// async global->LDS, 16B per lane, LDS dest = wave-uniform base + lane*16
__device__ inline void gload_lds16(const __hip_bfloat16* g, __hip_bfloat16* l) {
  __builtin_amdgcn_global_load_lds((const __attribute__((address_space(1))) void*)g,
                                   (__attribute__((address_space(3))) void*)l,
                                   16, 0, 0);
}

__device__ inline short f2bf(float f) {
  __hip_bfloat16 h = __float2bfloat16(f);
  return *reinterpret_cast<short*>(&h);
}
__device__ inline float bf2f(short s) {
  __hip_bfloat16 h = *reinterpret_cast<__hip_bfloat16*>(&s);
  return __bfloat162float(h);
}

// wait lgkmcnt(0) only; leave vmcnt/expcnt unconstrained
#define WAIT_LGKM0() __builtin_amdgcn_s_waitcnt(0xC07F)

// ---------------------------------------------------------------------------
// Kernel 0: split-precision transposed weights. Block 0 also zeroes maxk2.
// ---------------------------------------------------------------------------
__global__ void prep_w(const float* __restrict__ Wq, const float* __restrict__ Wk,
                       const float* __restrict__ Wv,
                       __hip_bfloat16* __restrict__ Wthi,
                       __hip_bfloat16* __restrict__ Wtlo,
                       float* __restrict__ maxk2) {
  const int n = blockIdx.x;          // 0..191
  if (n == 0 && threadIdx.x < 8) maxk2[threadIdx.x] = 0.f;
  const int m = n >> 6;
  const int h = n & 63;
  const float* W = (m == 0) ? Wq : (m == 1) ? Wk : Wv;
  const int e0 = threadIdx.x * 4;    // 256 threads * 4 = 1024
#pragma unroll
  for (int j = 0; j < 4; ++j) {
    const float w = W[(e0 + j) * 64 + h];
    const __hip_bfloat16 hi = __float2bfloat16(w);
    Wthi[n * 1024 + e0 + j] = hi;
    Wtlo[n * 1024 + e0 + j] = __float2bfloat16(w - __bfloat162float(hi));
  }
}

// ---------------------------------------------------------------------------
// Kernel A v2 (unchanged): 512 blocks x 32 rows, Blo in registers.
// ---------------------------------------------------------------------------
__global__ __launch_bounds__(256) void qkv_gemm(
    const float* __restrict__ x,
    const __hip_bfloat16* __restrict__ Wthi, const __hip_bfloat16* __restrict__ Wtlo,
    __hip_bfloat16* __restrict__ qhi, __hip_bfloat16* __restrict__ qlo,
    __hip_bfloat16* __restrict__ khi, __hip_bfloat16* __restrict__ klo,
    __hip_bfloat16* __restrict__ vT) {
  __shared__ __hip_bfloat16 Ahi[2][32 * 72];
  __shared__ __hip_bfloat16 Alo[2][32 * 72];
  __shared__ __hip_bfloat16 Bhi[2][192 * 64];

  const int tid  = threadIdx.x;
  const int wave = tid >> 6;
  const int lane = tid & 63;
  const int row0 = blockIdx.x * 32;
  const int l15 = lane & 15, l4 = lane >> 4;

  const int lr = tid >> 3;           // 0..31 (row in strip)
  const int le = (tid & 7) * 8;      // 0..56 (col, floats)
  const float* xrow = x + (row0 + lr) * 1024 + le;

  f32x4 acc[2][3];
#pragma unroll
  for (int m = 0; m < 2; ++m)
#pragma unroll
    for (int j = 0; j < 3; ++j) acc[m][j] = f32x4{0.f, 0.f, 0.f, 0.f};

  auto issue_Bhi = [&](int c, int buf) {
    const int g = (lane & 7) ^ ((lane >> 3) & 7);
#pragma unroll
    for (int s = 0; s < 3; ++s) {
      const int j = wave + s * 4;
#pragma unroll
      for (int qh = 0; qh < 2; ++qh) {
        const int qq = j * 2 + qh;
        const int n  = qq * 8 + (lane >> 3);
        gload_lds16(Wthi + n * 1024 + c * 64 + g * 8, &Bhi[buf][qq * 512]);
      }
    }
  };
  auto load_Blo = [&](int c, short8* bl) {
#pragma unroll
    for (int jj = 0; jj < 2; ++jj) {
      const int j = wave + jj * 4;
      const __hip_bfloat16* p = Wtlo + (j * 16 + l15) * 1024 + c * 64;
      bl[jj * 2]     = *(const short8*)(p + l4 * 8);
      bl[jj * 2 + 1] = *(const short8*)(p + 32 + l4 * 8);
    }
  };
  auto write_A = [&](int buf, const f32x4* xr) {
    short8 h0, l0;
    const float* xf = (const float*)xr;
#pragma unroll
    for (int j = 0; j < 8; ++j) {
      const float v = xf[j];
      const short h = f2bf(v);
      h0[j] = h;
      l0[j] = f2bf(v - bf2f(h));
    }
    *(short8*)&Ahi[buf][lr * 72 + le] = h0;
    *(short8*)&Alo[buf][lr * 72 + le] = l0;
  };
  auto compute = [&](int buf, const short8* bl) {
#pragma unroll
    for (int m = 0; m < 2; ++m) {
      const int tr = m * 16 + l15;
      short8 ah0 = *(const short8*)&Ahi[buf][tr * 72 + l4 * 8];
      short8 ah1 = *(const short8*)&Ahi[buf][tr * 72 + 32 + l4 * 8];
      short8 al0 = *(const short8*)&Alo[buf][tr * 72 + l4 * 8];
      short8 al1 = *(const short8*)&Alo[buf][tr * 72 + 32 + l4 * 8];
#pragma unroll
      for (int jj = 0; jj < 3; ++jj) {
        const int j  = (jj < 2) ? (wave + jj * 4) : (wave + 8);
        const int n  = j * 16 + l15;
        const int o0 = ((l4)     ^ (n & 7)) * 8;
        const int o1 = ((4 + l4) ^ (n & 7)) * 8;
        short8 bh0 = *(const short8*)&Bhi[buf][n * 64 + o0];
        short8 bh1 = *(const short8*)&Bhi[buf][n * 64 + o1];
        acc[m][jj] = mfma_16x16x32(ah0, bh0, acc[m][jj]);
        acc[m][jj] = mfma_16x16x32(ah1, bh1, acc[m][jj]);
        if (jj < 2) {
          acc[m][jj] = mfma_16x16x32(ah0, bl[jj * 2],     acc[m][jj]);
          acc[m][jj] = mfma_16x16x32(ah1, bl[jj * 2 + 1], acc[m][jj]);
          acc[m][jj] = mfma_16x16x32(al0, bh0, acc[m][jj]);
          acc[m][jj] = mfma_16x16x32(al1, bh1, acc[m][jj]);
        }
      }
    }
  };

  f32x4 xr[2], xn[2];
  {
    const f32x4* p = (const f32x4*)xrow;
    xr[0] = p[0]; xr[1] = p[1];
  }
  short8 blc[4], bln[4];
  issue_Bhi(0, 0);
  load_Blo(0, blc);
  __builtin_amdgcn_s_waitcnt(0);
  write_A(0, xr);
  __syncthreads();

  for (int c = 0; c < 16; ++c) {
    const int p = c & 1;
    if (c < 15) {
      const f32x4* pp = (const f32x4*)(xrow + (c + 1) * 64);
      xn[0] = pp[0]; xn[1] = pp[1];
      issue_Bhi(c + 1, p ^ 1);
      load_Blo(c + 1, bln);
    }
    compute(p, blc);
    if (c < 15) {
      __builtin_amdgcn_s_waitcnt(0);
      write_A(p ^ 1, xn);
#pragma unroll
      for (int q = 0; q < 4; ++q) blc[q] = bln[q];
    }
    __syncthreads();
  }

  const int hcol = wave * 16 + l15;
#pragma unroll
  for (int jj = 0; jj < 3; ++jj) {
#pragma unroll
    for (int m = 0; m < 2; ++m) {
#pragma unroll
      for (int r = 0; r < 4; ++r) {
        const int trow = row0 + m * 16 + l4 * 4 + r;
        const float val = acc[m][jj][r];
        if (jj == 0) {
          const __hip_bfloat16 hi = __float2bfloat16(val);
          qhi[trow * 64 + hcol] = hi;
          qlo[trow * 64 + hcol] = __float2bfloat16(val - __bfloat162float(hi));
        } else if (jj == 1) {
          const __hip_bfloat16 hi = __float2bfloat16(val);
          khi[trow * 64 + hcol] = hi;
          klo[trow * 64 + hcol] = __float2bfloat16(val - __bfloat162float(hi));
        } else {
          const int bb = trow >> 11, tl = trow & 2047;
          vT[(bb * 64 + hcol) * 2048 + tl] = __float2bfloat16(val);
        }
      }
    }
  }
}

// ---------------------------------------------------------------------------
// Kernel K: per-batch max |k_row|^2 via int-bits atomicMax (k2 >= 0).
// ---------------------------------------------------------------------------
__global__ __launch_bounds__(256) void knorm(
    const __hip_bfloat16* __restrict__ khi, const __hip_bfloat16* __restrict__ klo,
    float* __restrict__ maxk2) {
  const int row = blockIdx.x * 256 + threadIdx.x;   // 0..16383
  const int b = row >> 11;
  const __hip_bfloat16* ph = khi + row * 64;
  const __hip_bfloat16* pl = klo + row * 64;
  float s = 0.f;
#pragma unroll
  for (int i = 0; i < 8; ++i) {
    const short8 h = *(const short8*)(ph + i * 8);
    const short8 l = *(const short8*)(pl + i * 8);
#pragma unroll
    for (int j = 0; j < 8; ++j) {
      const float v = bf2f(h[j]) + bf2f(l[j]);
      s += v * v;
    }
  }
  for (int off = 1; off < 64; off <<= 1) s = fmaxf(s, __shfl_xor(s, off));
  if ((threadIdx.x & 63) == 0)
    atomicMax((int*)&maxk2[b], __float_as_int(s));
}

// ---------------------------------------------------------------------------
// Kernel B v11: 32-row wave-tiles + in-wave pipeline + balanced strip map.
// v10 post-mortem: all pipes idle; cost = per-tile serial chain x tile count.
// Fixes: (1) 32 Q-rows/tile (halves tile count vs v10; v6-geometry evidence
// 41.5 vs 56.5us); (2) prefetch next tile's K right after QK consumes K, V
// issued before m=1 softmax -> both vmcnt stalls hidden under exp/P/PV;
// (3) ss = (g<32)?63-g:g-32 makes each CU's 2 blocks sum ~34 tiles (was
// 50..19 imbalance). Keeps v10's short chain: bound-subtract softmax (no
// shuffles, no rescale), MFMA row-sum L, plain-sum merge.
// lb(256,2) only -- (256,4) pins VGPR=64 and spills (v8: 280MB WRITE_SIZE).
// ---------------------------------------------------------------------------
__global__ __launch_bounds__(256, 2) void attn(
    const __hip_bfloat16* __restrict__ qhi, const __hip_bfloat16* __restrict__ qlo,
    const __hip_bfloat16* __restrict__ khi, const __hip_bfloat16* __restrict__ klo,
    const __hip_bfloat16* __restrict__ vT, const float* __restrict__ maxk2,
    float* __restrict__ out) {
  __shared__ __hip_bfloat16 Psm[4][2][16 * 72];  // per-wave, per-m P transpose
  __shared__ float Osm[4][32][65];               // per-wave partial O (fp32)
  __shared__ float Lsm[4][32];                   // per-wave partial L

  const int tid  = threadIdx.x;
  const int wave = tid >> 6;
  const int lane = tid & 63;
  const int l15 = lane & 15, l4 = lane >> 4;

  const int b = blockIdx.x & 7;              // XCD-local batch
  const int g = blockIdx.x >> 3;             // 0..63
  const int ss = (g < 32) ? (63 - g) : (g - 32);  // CU's 2 blocks sum ~const
  const int t0 = ss * 32;
  const int ntiles = (ss >> 1) + 1;          // causal 64-key tiles

  // ---- Q A-frags for 2 m sub-tiles, hi+lo (32 VGPRs) ----
  short8 qh0[2], qh1[2], ql0[2], ql1[2];
#pragma unroll
  for (int m = 0; m < 2; ++m) {
    const __hip_bfloat16* qph = qhi + (b * 2048 + t0 + m * 16 + l15) * 64;
    const __hip_bfloat16* qpl = qlo + (b * 2048 + t0 + m * 16 + l15) * 64;
    qh0[m] = *(const short8*)(qph + l4 * 8);
    qh1[m] = *(const short8*)(qph + 32 + l4 * 8);
    ql0[m] = *(const short8*)(qpl + l4 * 8);
    ql1[m] = *(const short8*)(qpl + 32 + l4 * 8);
  }

  // ---- per-row Cauchy-Schwarz bound c_r = |q_r| * kmax + 2 ----
  const float kmax = sqrtf(maxk2[b]);
  float c_[2][4];
#pragma unroll
  for (int m = 0; m < 2; ++m) {
    float qn = 0.f;
#pragma unroll
    for (int i = 0; i < 8; ++i) {
      const float v0 = bf2f(qh0[m][i]) + bf2f(ql0[m][i]);
      const float v1 = bf2f(qh1[m][i]) + bf2f(ql1[m][i]);
      qn += v0 * v0 + v1 * v1;
    }
    qn += __shfl_xor(qn, 16);
    qn += __shfl_xor(qn, 32);                // |q_{t0+m*16+l15}|^2
    const float crow = sqrtf(qn) * kmax + 2.0f;
#pragma unroll
    for (int r = 0; r < 4; ++r) c_[m][r] = __shfl(crow, l4 * 4 + r);
  }

  short8 ones;                                // bf16 1.0 x8 (B-frag for L)
#pragma unroll
  for (int i = 0; i < 8; ++i) ones[i] = (short)0x3F80;

  f32x4 acc[2][4];
#pragma unroll
  for (int m = 0; m < 2; ++m)
#pragma unroll
    for (int j = 0; j < 4; ++j) acc[m][j] = f32x4{0.f, 0.f, 0.f, 0.f};
  f32x4 accL[2];
  accL[0] = f32x4{0.f, 0.f, 0.f, 0.f};
  accL[1] = f32x4{0.f, 0.f, 0.f, 0.f};

  const __hip_bfloat16* kbase_h = khi + (size_t)b * 2048 * 64;
  const __hip_bfloat16* kbase_l = klo + (size_t)b * 2048 * 64;
  const __hip_bfloat16* vbase   = vT + (size_t)b * 64 * 2048;

  // K frags for the wave's CURRENT tile (reused as prefetch destination)
  short8 kh0[4], kh1[4], kl0[4], kl1[4];
  auto load_K = [&](int k0) {
#pragma unroll
    for (int j = 0; j < 4; ++j) {
      const __hip_bfloat16* kph = kbase_h + (k0 + j * 16 + l15) * 64;
      const __hip_bfloat16* kpl = kbase_l + (k0 + j * 16 + l15) * 64;
      kh0[j] = *(const short8*)(kph + l4 * 8);
      kh1[j] = *(const short8*)(kph + 32 + l4 * 8);
      kl0[j] = *(const short8*)(kpl + l4 * 8);
      kl1[j] = *(const short8*)(kpl + 32 + l4 * 8);
    }
  };

  if (wave < ntiles) load_K(wave << 6);      // prologue prefetch

  for (int kt = wave; kt < ntiles; kt += 4) {
    const int k0 = kt << 6;
    const bool diag = (kt == ntiles - 1);

    // ---- QK + softmax for m=0 (s dies before m=1's lives: caps regs) ----
    f32x4 s_[4];
#pragma unroll
    for (int m = 0; m < 2; ++m) {
      const int rowmax = t0 + m * 16 + 15;
#pragma unroll
      for (int j = 0; j < 4; ++j) {
        if (diag && (k0 + j * 16) > rowmax) {
          s_[j] = f32x4{-1e30f, -1e30f, -1e30f, -1e30f};
        } else {
          f32x4 z = f32x4{0.f, 0.f, 0.f, 0.f};
          z = mfma_16x16x32(qh0[m], kh0[j], z);
          z = mfma_16x16x32(qh1[m], kh1[j], z);
          z = mfma_16x16x32(qh0[m], kl0[j], z);
          z = mfma_16x16x32(qh1[m], kl1[j], z);
          z = mfma_16x16x32(ql0[m], kh0[j], z);
          z = mfma_16x16x32(ql1[m], kh1[j], z);
          s_[j] = z;
        }
      }
      if (m == 1) break;  // m=1: V + prefetch issued before its softmax below
      if (diag) {
#pragma unroll
        for (int j = 0; j < 4; ++j) {
          const int key = k0 + j * 16 + l15;
#pragma unroll
          for (int r = 0; r < 4; ++r)
            if (key > (t0 + l4 * 4 + r)) s_[j][r] = -1e30f;
        }
      }
#pragma unroll
      for (int j = 0; j < 4; ++j)
#pragma unroll
        for (int r = 0; r < 4; ++r) {
          const float pv = __expf(s_[j][r] - c_[0][r]);
          Psm[wave][0][(l4 * 4 + r) * 72 + j * 16 + l15] = __float2bfloat16(pv);
        }
    }

    // ---- V loads for this tile (latency hidden by m=1 softmax + P wait) ----
    short8 vf0[4], vf1[4];
#pragma unroll
    for (int j = 0; j < 4; ++j) {
      const __hip_bfloat16* vp = vbase + (j * 16 + l15) * 2048 + k0;
      vf0[j] = *(const short8*)(vp + l4 * 8);
      vf1[j] = *(const short8*)(vp + 32 + l4 * 8);
    }
    // ---- prefetch next tile's K (K regs free: QK done for both m) ----
    if (kt + 4 < ntiles) load_K((kt + 4) << 6);

    // ---- m=1 softmax (s_ holds m=1 scores) ----
    if (diag) {
#pragma unroll
      for (int j = 0; j < 4; ++j) {
        const int key = k0 + j * 16 + l15;
#pragma unroll
        for (int r = 0; r < 4; ++r)
          if (key > (t0 + 16 + l4 * 4 + r)) s_[j][r] = -1e30f;
      }
    }
#pragma unroll
    for (int j = 0; j < 4; ++j)
#pragma unroll
      for (int r = 0; r < 4; ++r) {
        const float pv = __expf(s_[j][r] - c_[1][r]);
        Psm[wave][1][(l4 * 4 + r) * 72 + j * 16 + l15] = __float2bfloat16(pv);
      }

    WAIT_LGKM0();   // all 32 P writes visible to same wave; vmcnt untouched

    // ---- O += P V ; L += P . 1 ----
#pragma unroll
    for (int m = 0; m < 2; ++m) {
      const short8 pf0 = *(const short8*)&Psm[wave][m][l15 * 72 + l4 * 8];
      const short8 pf1 = *(const short8*)&Psm[wave][m][l15 * 72 + 32 + l4 * 8];
#pragma unroll
      for (int j = 0; j < 4; ++j) {
        acc[m][j] = mfma_16x16x32(pf0, vf0[j], acc[m][j]);
        acc[m][j] = mfma_16x16x32(pf1, vf1[j], acc[m][j]);
      }
      accL[m] = mfma_16x16x32(pf0, ones, accL[m]);
      accL[m] = mfma_16x16x32(pf1, ones, accL[m]);
    }
  }

  // ---- per-wave partials into LDS (fp32, plain sums) ----
#pragma unroll
  for (int m = 0; m < 2; ++m) {
#pragma unroll
    for (int j = 0; j < 4; ++j)
#pragma unroll
      for (int r = 0; r < 4; ++r)
        Osm[wave][m * 16 + l4 * 4 + r][j * 16 + l15] = acc[m][j][r];
    if (l15 == 0) {
#pragma unroll
      for (int r = 0; r < 4; ++r)
        Lsm[wave][m * 16 + l4 * 4 + r] = accL[m][r];
    }
  }
  __syncthreads();

  // ---- cross-wave merge: PLAIN SUM (c_r uniform per row -> exact) ----
#pragma unroll
  for (int rr = 0; rr < 8; ++rr) {
    const int row = wave * 8 + rr;
    const float L = Lsm[0][row] + Lsm[1][row] + Lsm[2][row] + Lsm[3][row];
    const float O = Osm[0][row][lane] + Osm[1][row][lane] +
                    Osm[2][row][lane] + Osm[3][row][lane];
    out[(b * 2048 + t0 + row) * 64 + lane] = O / L;
  }
}

// ---------------------------------------------------------------------------
extern "C" void kernel_launch(void* const* d_in, const int* in_sizes, int n_in,
                              void* d_out, int out_size, void* d_ws, size_t ws_size,
                              hipStream_t stream) {
  const float* x  = (const float*)d_in[0];
  const float* Wq = (const float*)d_in[1];
  const float* Wk = (const float*)d_in[2];
  const float* Wv = (const float*)d_in[3];
  float* out = (float*)d_out;

  char* ws = (char*)d_ws;
  __hip_bfloat16* Wthi = (__hip_bfloat16*)ws;                   // 384 KB
  __hip_bfloat16* Wtlo = (__hip_bfloat16*)(ws + 393216);        // 384 KB
  __hip_bfloat16* qhi  = (__hip_bfloat16*)(ws + 786432);        // 2 MB each
  __hip_bfloat16* qlo  = (__hip_bfloat16*)(ws + 786432 + 1 * 2097152);
  __hip_bfloat16* khi  = (__hip_bfloat16*)(ws + 786432 + 2 * 2097152);
  __hip_bfloat16* klo  = (__hip_bfloat16*)(ws + 786432 + 3 * 2097152);
  __hip_bfloat16* vT   = (__hip_bfloat16*)(ws + 786432 + 4 * 2097152);
  float* maxk2         = (float*)(ws + 786432 + 5 * 2097152);   // 32 B

  prep_w<<<192, 256, 0, stream>>>(Wq, Wk, Wv, Wthi, Wtlo, maxk2);
  qkv_gemm<<<512, 256, 0, stream>>>(x, Wthi, Wtlo, qhi, qlo, khi, klo, vT);
  knorm<<<64, 256, 0, stream>>>(khi, klo, maxk2);
  attn<<<512, 256, 0, stream>>>(qhi, qlo, khi, klo, vT, maxk2, out);  // 8 x 64
}